// Round 5
// baseline (761.029 us; speedup 1.0000x reference)
//
#include <hip/hip_runtime.h>
#include <hip/hip_bf16.h>

// MPNN fused pipeline, bf16 MFMA (16x16x32), fp32 accum.
// R5 changes vs R4 (fused latency-bound at 8 waves/CU; no pipe >40% busy):
//  - j-tile 64 -> 32: Ks dbuf 2x16KB + Ps dbuf 2x4KB = 40KB LDS
//    -> 4 blocks/CU = 16 waves/CU (launch_bounds(256,4)). Per-j-row LDS,
//    MFMA and L1 traffic unchanged; PV is a single K=32 MFMA step.
//  - e1/e2 GEMMs fused into one dispatch (grid.z selects W/bias/out).

typedef short bf16x8  __attribute__((ext_vector_type(8)));
typedef short short4v __attribute__((ext_vector_type(4)));
typedef float f32x4   __attribute__((ext_vector_type(4)));

__device__ inline short f2bf(float x) {                // fp32 -> bf16 RNE
    unsigned u = __builtin_bit_cast(unsigned, x);
    return (short)((u + 0x7fffu + ((u >> 16) & 1u)) >> 16);
}

__device__ inline void cp16_async(const short* g, short* l) {
    __builtin_amdgcn_global_load_lds(
        (const __attribute__((address_space(1))) unsigned int*)g,
        (__attribute__((address_space(3))) unsigned int*)l, 16, 0, 0);
}

// ---------------------------------------------------------------- prep_x
__global__ void prep_x(const float* __restrict__ X, short* __restrict__ h,
                       int ldh, short* __restrict__ Xt)
{
    __shared__ short tile[32][33];
    const int r0 = blockIdx.x * 32, c0 = blockIdx.y * 32;
    const int tx = threadIdx.x, ty = threadIdx.y;      // 32 x 8
    #pragma unroll
    for (int i = 0; i < 4; ++i) {
        int row = ty + i * 8;
        short b = f2bf(X[(size_t)(r0 + row) * 256 + c0 + tx]);
        tile[row][tx] = b;
        h[(size_t)(r0 + row) * ldh + c0 + tx] = b;
    }
    __syncthreads();
    #pragma unroll
    for (int i = 0; i < 4; ++i) {
        int row = ty + i * 8;
        Xt[(size_t)(c0 + row) * 8192 + r0 + tx] = tile[tx][row];
    }
}

// -------------------------------------------------------------- prep_w_all
__global__ void prep_w_all(const float* __restrict__ W1,
                           const float* __restrict__ W2,
                           const float* __restrict__ Wo,
                           short* __restrict__ Wt1, short* __restrict__ Wt2,
                           short* __restrict__ Wto, int H, int js)
{
    const int z = blockIdx.z;
    const float* src; short* dst; int ldwt, k_off;
    if (z == 0)      { src = W1; dst = Wt1; ldwt = 256; k_off = 0; }
    else if (z == 1) { src = W2; dst = Wt2; ldwt = 256; k_off = 0; }
    else {
        int g = z - 2;                         // 0 .. 2*js
        int srcrow = (g == 0) ? 0 : (g <= js ? 256 : 512);
        src = Wo + (size_t)srcrow * 256; dst = Wto; ldwt = H; k_off = g * 256;
    }
    __shared__ short tile[32][33];
    const int k0 = blockIdx.x * 32, n0 = blockIdx.y * 32;
    const int tx = threadIdx.x, ty = threadIdx.y;
    #pragma unroll
    for (int i = 0; i < 4; ++i) {
        int row = ty + i * 8;
        tile[row][tx] = f2bf(src[(size_t)(k0 + row) * 256 + n0 + tx]);
    }
    __syncthreads();
    #pragma unroll
    for (int i = 0; i < 4; ++i) {
        int row = ty + i * 8;
        dst[(size_t)(n0 + row) * ldwt + k_off + k0 + tx] = tile[tx][row];
    }
}

// -------------------------------------------------------- gemm_bias_relu
__global__ __launch_bounds__(256, 1)
void gemm_bias_relu(const short* __restrict__ A, int lda,
                    const short* __restrict__ Bt0, const short* __restrict__ Bt1,
                    int K,
                    const float* __restrict__ bias0, const float* __restrict__ bias1,
                    void* __restrict__ out0, void* __restrict__ out1,
                    int out_bf16, int ldo, int swz)
{
    const short* Bt   = blockIdx.z ? Bt1   : Bt0;
    const float* bias = blockIdx.z ? bias1 : bias0;
    void*        outp = blockIdx.z ? out1  : out0;

    const int m0 = blockIdx.x * 64, n0 = blockIdx.y * 64;
    const int t = threadIdx.x;
    const int w = t >> 6, l = t & 63, lr = l & 15, q = l >> 4;

    __shared__ __attribute__((aligned(16))) short As[64 * 64];
    __shared__ __attribute__((aligned(16))) short Bs[64 * 64];

    f32x4 acc[4];
    #pragma unroll
    for (int i = 0; i < 4; ++i) acc[i] = f32x4{0.f, 0.f, 0.f, 0.f};

    for (int k0 = 0; k0 < K; k0 += 64) {
        __syncthreads();
        for (int i = t; i < 64 * 8; i += 256) {
            int row = i >> 3, g = i & 7;
            *(int4*)&As[row * 64 + ((g ^ (row & 7)) << 3)] =
                *(const int4*)(A + (size_t)(m0 + row) * lda + k0 + g * 8);
            *(int4*)&Bs[row * 64 + ((g ^ (row & 7)) << 3)] =
                *(const int4*)(Bt + (size_t)(n0 + row) * K + k0 + g * 8);
        }
        __syncthreads();
        #pragma unroll
        for (int ks = 0; ks < 2; ++ks) {
            int arow = w * 16 + lr;
            bf16x8 af = *(const bf16x8*)&As[arow * 64 + (((ks*4 + q) ^ (arow & 7)) << 3)];
            #pragma unroll
            for (int nt = 0; nt < 4; ++nt) {
                int brow = nt * 16 + lr;
                bf16x8 bfg = *(const bf16x8*)&Bs[brow * 64 + (((ks*4 + q) ^ (brow & 7)) << 3)];
                acc[nt] = __builtin_amdgcn_mfma_f32_16x16x32_bf16(af, bfg, acc[nt], 0, 0, 0);
            }
        }
    }
    #pragma unroll
    for (int nt = 0; nt < 4; ++nt)
        #pragma unroll
        for (int r = 0; r < 4; ++r) {
            int m = m0 + w * 16 + q * 4 + r;      // C/D: row = quad*4 + reg
            int n = n0 + nt * 16 + lr;            //      col = lane & 15
            float v = acc[nt][r] + bias[n];
            v = v > 0.f ? v : 0.f;
            if (out_bf16) {
                int col = swz ? ((((n >> 3) ^ (m & 7)) << 3) | (n & 7)) : n;
                ((short*)outp)[(size_t)m * ldo + col] = f2bf(v);
            } else {
                ((float*)outp)[(size_t)m * ldo + n] = v;
            }
        }
}

// ---------------------------------------------------------- fused_simagg
// j-tile = 32 rows; Ks/Ps double-buffered; one barrier per tile; 40KB LDS.
__global__ __launch_bounds__(256, 4)
void fused_simagg(const short* __restrict__ e1, const short* __restrict__ e2,
                  const short* __restrict__ Xt, short* __restrict__ h,
                  int ldh, int tiles_per_split)
{
    // XCD swizzle: grid (128,2,2) -> each (sim,jz) quadrant on 2 fixed XCDs.
    int sim, jz, mx;
    if (gridDim.x == 128 && gridDim.z == 2) {
        int flat = blockIdx.x + 128 * (blockIdx.y + 2 * blockIdx.z);
        int xcd = flat & 7, slot = flat >> 3;
        int quad = xcd >> 1;
        sim = quad >> 1; jz = quad & 1;
        mx = slot + (xcd & 1) * 64;
    } else { sim = blockIdx.y; jz = blockIdx.z; mx = blockIdx.x; }

    const short* e = sim ? e2 : e1;
    const int m0 = mx * 64;
    const int t = threadIdx.x;
    const int w = t >> 6, l = t & 63, lr = l & 15, q = l >> 4;
    const int mh = (w & 1) * 32;               // m-half of this wave
    const int jq = (w >> 1) * 16;              // j-half (16 rows) of the tile

    __shared__ __attribute__((aligned(16))) short Ks[2][32 * 256]; // 32 KB
    __shared__ __attribute__((aligned(16))) short Ps[2][64 * 32];  //  8 KB

    // Q frags: rows m0 + mh + ms*16 + lr (compiler may stream from L1)
    bf16x8 qf[2][8];
    #pragma unroll
    for (int ms = 0; ms < 2; ++ms) {
        const int mrow = m0 + mh + ms * 16 + lr;
        const short* qrow = e + (size_t)mrow * 256;
        #pragma unroll
        for (int kc = 0; kc < 8; ++kc)
            qf[ms][kc] = *(const bf16x8*)(qrow + (((kc * 4 + q) ^ (mrow & 7)) << 3));
    }

    f32x4 agg[16];
    #pragma unroll
    for (int i = 0; i < 16; ++i) agg[i] = f32x4{0.f, 0.f, 0.f, 0.f};

    const int jbase = jz * tiles_per_split;
    const int wub = t & ~63;                   // wave-uniform thread base

    // prologue: stage tile 0 (16 KB) into Ks[0]
    {
        const short* src = e + (size_t)(jbase * 32) * 256;
        #pragma unroll
        for (int it = 0; it < 4; ++it)
            cp16_async(src + (size_t)(it * 256 + t) * 8,
                       &Ks[0][(size_t)(it * 256 + wub) * 8]);
    }
    __syncthreads();

    for (int jt = 0; jt < tiles_per_split; ++jt) {
        const int cur = jt & 1, nxt = cur ^ 1;
        const int j0 = (jbase + jt) * 32;

        // async prefetch of next K tile (drains at the barrier)
        if (jt + 1 < tiles_per_split) {
            const short* src = e + (size_t)(j0 + 32) * 256;
            #pragma unroll
            for (int it = 0; it < 4; ++it)
                cp16_async(src + (size_t)(it * 256 + t) * 8,
                           &Ks[nxt][(size_t)(it * 256 + wub) * 8]);
        }

        // vf register prefetch (B-frag of V, K=32 = whole tile)
        bf16x8 vfr[4];
        #pragma unroll
        for (int nt = 0; nt < 4; ++nt) {
            int n = w * 64 + nt * 16 + lr;
            vfr[nt] = *(const bf16x8*)(Xt + (size_t)n * 8192 + j0 + q * 8);
        }

        // S^T quadrant: wave reads only its 16 K-rows (jq .. jq+15)
        const short* Kb = &Ks[cur][0];
        f32x4 s[2];
        s[0] = f32x4{0.f, 0.f, 0.f, 0.f};
        s[1] = f32x4{0.f, 0.f, 0.f, 0.f};
        #pragma unroll
        for (int kc = 0; kc < 8; ++kc) {
            int row = jq + lr;
            bf16x8 kf = *(const bf16x8*)&Kb[row * 256 + (((kc*4 + q) ^ (row & 7)) << 3)];
            #pragma unroll
            for (int ms = 0; ms < 2; ++ms)
                s[ms] = __builtin_amdgcn_mfma_f32_16x16x32_bf16(
                    kf, qf[ms][kc], s[ms], 0, 0, 0);
        }

        // P scatter: 4 consecutive j at fixed m -> one aligned b64 each
        #pragma unroll
        for (int ms = 0; ms < 2; ++ms) {
            int mloc = mh + ms * 16 + lr;
            int jj = jq + q * 4;
            int off = mloc * 32 + (((jj >> 3) ^ (mloc & 3)) << 3) + (jj & 7);
            short4v pk = { f2bf(s[ms][0] * (1.0f/256.0f)),
                           f2bf(s[ms][1] * (1.0f/256.0f)),
                           f2bf(s[ms][2] * (1.0f/256.0f)),
                           f2bf(s[ms][3] * (1.0f/256.0f)) };
            *(short4v*)&Ps[cur][off] = pk;
        }
        __syncthreads();   // the ONLY barrier per tile

        // agg += P V : single K=32 step; pf from Ps[cur], vf prefetched
        bf16x8 pf[4];
        #pragma unroll
        for (int mt = 0; mt < 4; ++mt) {
            int row = mt * 16 + lr;
            pf[mt] = *(const bf16x8*)&Ps[cur][row * 32 + ((q ^ (row & 3)) << 3)];
        }
        #pragma unroll
        for (int nt = 0; nt < 4; ++nt) {
            #pragma unroll
            for (int mt = 0; mt < 4; ++mt)
                agg[mt * 4 + nt] = __builtin_amdgcn_mfma_f32_16x16x32_bf16(
                    pf[mt], vfr[nt], agg[mt * 4 + nt], 0, 0, 0);
        }
    }

    const int colbase = 256 + (sim * gridDim.z + jz) * 256;
    #pragma unroll
    for (int mt = 0; mt < 4; ++mt)
        #pragma unroll
        for (int nt = 0; nt < 4; ++nt)
            #pragma unroll
            for (int r = 0; r < 4; ++r) {
                int m = m0 + mt * 16 + q * 4 + r;
                int n = w * 64 + nt * 16 + lr;
                h[(size_t)m * ldh + colbase + n] = f2bf(agg[mt * 4 + nt][r]);
            }
}

// ---------------------------------------------------------------- launch
extern "C" void kernel_launch(void* const* d_in, const int* in_sizes, int n_in,
                              void* d_out, int out_size, void* d_ws, size_t ws_size,
                              hipStream_t stream)
{
    const float* edge_x = (const float*)d_in[0];
    const float* W1 = (const float*)d_in[1];
    const float* b1 = (const float*)d_in[2];
    const float* W2 = (const float*)d_in[3];
    const float* b2 = (const float*)d_in[4];
    const float* Wo = (const float*)d_in[5];
    const float* bo = (const float*)d_in[6];

    const size_t need2 = (size_t)8192*1280*2 + 4194304u*3 + 131072u*2 + (size_t)1280*256*2;
    const int js = (ws_size >= need2) ? 2 : 1;
    const int H = 256 + 2 * js * 256;              // 1280 or 768

    char* ws = (char*)d_ws;
    short* h   = (short*)ws;
    short* Xt  = (short*)(ws + (size_t)8192 * H * 2);
    short* e1  = (short*)((char*)Xt + 4194304);
    short* e2  = (short*)((char*)e1 + 4194304);
    short* Wt1 = (short*)((char*)e2 + 4194304);
    short* Wt2 = (short*)((char*)Wt1 + 131072);
    short* Wto = (short*)((char*)Wt2 + 131072);

    prep_x<<<dim3(256, 8), dim3(32, 8), 0, stream>>>(edge_x, h, H, Xt);
    prep_w_all<<<dim3(8, 8, 3 + 2 * js), dim3(32, 8), 0, stream>>>(
        W1, W2, Wo, Wt1, Wt2, Wto, H, js);

    // e1 and e2 GEMMs in one dispatch (grid.z)
    gemm_bias_relu<<<dim3(128, 4, 2), 256, 0, stream>>>(
        h, H, Wt1, Wt2, 256, b1, b2, e1, e2, 1, 256, 1);
    // j-tiles of 32 rows: (8192/32)/js per split
    fused_simagg<<<dim3(128, 2, js), 256, 0, stream>>>(e1, e2, Xt, h, H, 256 / js);
    gemm_bias_relu<<<dim3(128, 4, 1), 256, 0, stream>>>(
        h, H, Wto, Wto, H, bo, bo, (float*)d_out, (float*)d_out, 0, 256, 0);
}

// Round 6
// 330.913 us; speedup vs baseline: 2.2998x; 2.2998x over previous
//
#include <hip/hip_runtime.h>
#include <hip/hip_bf16.h>

// MPNN fused pipeline, bf16 MFMA (16x16x32), fp32 accum.
// R6 changes vs R5 (R5 = spill catastrophe: launch_bounds(256,4) capped the
// unified VGPR/AGPR file at 128/thread vs ~172 needed -> ~70 regs spilled in
// the jt loop -> FETCH 224MB scratch traffic, 675us):
//  - launch_bounds(256,3): cap ~170 regs -> 3 waves/SIMD = 12 waves/CU with
//    the 40KB LDS tile (registers were the binding constraint, not LDS).
//  - pf streamed one fragment at a time in PV (-12 live VGPRs, ~158 total).
//  - everything else identical to R5 (32-row j-tile, dbuf DMA staging,
//    quadrant QK partition, one barrier/tile, XCD swizzle).

typedef short bf16x8  __attribute__((ext_vector_type(8)));
typedef short short4v __attribute__((ext_vector_type(4)));
typedef float f32x4   __attribute__((ext_vector_type(4)));

__device__ inline short f2bf(float x) {                // fp32 -> bf16 RNE
    unsigned u = __builtin_bit_cast(unsigned, x);
    return (short)((u + 0x7fffu + ((u >> 16) & 1u)) >> 16);
}

__device__ inline void cp16_async(const short* g, short* l) {
    __builtin_amdgcn_global_load_lds(
        (const __attribute__((address_space(1))) unsigned int*)g,
        (__attribute__((address_space(3))) unsigned int*)l, 16, 0, 0);
}

// ---------------------------------------------------------------- prep_x
__global__ void prep_x(const float* __restrict__ X, short* __restrict__ h,
                       int ldh, short* __restrict__ Xt)
{
    __shared__ short tile[32][33];
    const int r0 = blockIdx.x * 32, c0 = blockIdx.y * 32;
    const int tx = threadIdx.x, ty = threadIdx.y;      // 32 x 8
    #pragma unroll
    for (int i = 0; i < 4; ++i) {
        int row = ty + i * 8;
        short b = f2bf(X[(size_t)(r0 + row) * 256 + c0 + tx]);
        tile[row][tx] = b;
        h[(size_t)(r0 + row) * ldh + c0 + tx] = b;
    }
    __syncthreads();
    #pragma unroll
    for (int i = 0; i < 4; ++i) {
        int row = ty + i * 8;
        Xt[(size_t)(c0 + row) * 8192 + r0 + tx] = tile[tx][row];
    }
}

// -------------------------------------------------------------- prep_w_all
__global__ void prep_w_all(const float* __restrict__ W1,
                           const float* __restrict__ W2,
                           const float* __restrict__ Wo,
                           short* __restrict__ Wt1, short* __restrict__ Wt2,
                           short* __restrict__ Wto, int H, int js)
{
    const int z = blockIdx.z;
    const float* src; short* dst; int ldwt, k_off;
    if (z == 0)      { src = W1; dst = Wt1; ldwt = 256; k_off = 0; }
    else if (z == 1) { src = W2; dst = Wt2; ldwt = 256; k_off = 0; }
    else {
        int g = z - 2;                         // 0 .. 2*js
        int srcrow = (g == 0) ? 0 : (g <= js ? 256 : 512);
        src = Wo + (size_t)srcrow * 256; dst = Wto; ldwt = H; k_off = g * 256;
    }
    __shared__ short tile[32][33];
    const int k0 = blockIdx.x * 32, n0 = blockIdx.y * 32;
    const int tx = threadIdx.x, ty = threadIdx.y;
    #pragma unroll
    for (int i = 0; i < 4; ++i) {
        int row = ty + i * 8;
        tile[row][tx] = f2bf(src[(size_t)(k0 + row) * 256 + n0 + tx]);
    }
    __syncthreads();
    #pragma unroll
    for (int i = 0; i < 4; ++i) {
        int row = ty + i * 8;
        dst[(size_t)(n0 + row) * ldwt + k_off + k0 + tx] = tile[tx][row];
    }
}

// -------------------------------------------------------- gemm_bias_relu
__global__ __launch_bounds__(256, 1)
void gemm_bias_relu(const short* __restrict__ A, int lda,
                    const short* __restrict__ Bt0, const short* __restrict__ Bt1,
                    int K,
                    const float* __restrict__ bias0, const float* __restrict__ bias1,
                    void* __restrict__ out0, void* __restrict__ out1,
                    int out_bf16, int ldo, int swz)
{
    const short* Bt   = blockIdx.z ? Bt1   : Bt0;
    const float* bias = blockIdx.z ? bias1 : bias0;
    void*        outp = blockIdx.z ? out1  : out0;

    const int m0 = blockIdx.x * 64, n0 = blockIdx.y * 64;
    const int t = threadIdx.x;
    const int w = t >> 6, l = t & 63, lr = l & 15, q = l >> 4;

    __shared__ __attribute__((aligned(16))) short As[64 * 64];
    __shared__ __attribute__((aligned(16))) short Bs[64 * 64];

    f32x4 acc[4];
    #pragma unroll
    for (int i = 0; i < 4; ++i) acc[i] = f32x4{0.f, 0.f, 0.f, 0.f};

    for (int k0 = 0; k0 < K; k0 += 64) {
        __syncthreads();
        for (int i = t; i < 64 * 8; i += 256) {
            int row = i >> 3, g = i & 7;
            *(int4*)&As[row * 64 + ((g ^ (row & 7)) << 3)] =
                *(const int4*)(A + (size_t)(m0 + row) * lda + k0 + g * 8);
            *(int4*)&Bs[row * 64 + ((g ^ (row & 7)) << 3)] =
                *(const int4*)(Bt + (size_t)(n0 + row) * K + k0 + g * 8);
        }
        __syncthreads();
        #pragma unroll
        for (int ks = 0; ks < 2; ++ks) {
            int arow = w * 16 + lr;
            bf16x8 af = *(const bf16x8*)&As[arow * 64 + (((ks*4 + q) ^ (arow & 7)) << 3)];
            #pragma unroll
            for (int nt = 0; nt < 4; ++nt) {
                int brow = nt * 16 + lr;
                bf16x8 bfg = *(const bf16x8*)&Bs[brow * 64 + (((ks*4 + q) ^ (brow & 7)) << 3)];
                acc[nt] = __builtin_amdgcn_mfma_f32_16x16x32_bf16(af, bfg, acc[nt], 0, 0, 0);
            }
        }
    }
    #pragma unroll
    for (int nt = 0; nt < 4; ++nt)
        #pragma unroll
        for (int r = 0; r < 4; ++r) {
            int m = m0 + w * 16 + q * 4 + r;      // C/D: row = quad*4 + reg
            int n = n0 + nt * 16 + lr;            //      col = lane & 15
            float v = acc[nt][r] + bias[n];
            v = v > 0.f ? v : 0.f;
            if (out_bf16) {
                int col = swz ? ((((n >> 3) ^ (m & 7)) << 3) | (n & 7)) : n;
                ((short*)outp)[(size_t)m * ldo + col] = f2bf(v);
            } else {
                ((float*)outp)[(size_t)m * ldo + n] = v;
            }
        }
}

// ---------------------------------------------------------- fused_simagg
// j-tile = 32 rows; Ks/Ps double-buffered; one barrier per tile; 40KB LDS.
__global__ __launch_bounds__(256, 3)
void fused_simagg(const short* __restrict__ e1, const short* __restrict__ e2,
                  const short* __restrict__ Xt, short* __restrict__ h,
                  int ldh, int tiles_per_split)
{
    // XCD swizzle: grid (128,2,2) -> each (sim,jz) quadrant on 2 fixed XCDs.
    int sim, jz, mx;
    if (gridDim.x == 128 && gridDim.z == 2) {
        int flat = blockIdx.x + 128 * (blockIdx.y + 2 * blockIdx.z);
        int xcd = flat & 7, slot = flat >> 3;
        int quad = xcd >> 1;
        sim = quad >> 1; jz = quad & 1;
        mx = slot + (xcd & 1) * 64;
    } else { sim = blockIdx.y; jz = blockIdx.z; mx = blockIdx.x; }

    const short* e = sim ? e2 : e1;
    const int m0 = mx * 64;
    const int t = threadIdx.x;
    const int w = t >> 6, l = t & 63, lr = l & 15, q = l >> 4;
    const int mh = (w & 1) * 32;               // m-half of this wave
    const int jq = (w >> 1) * 16;              // j-half (16 rows) of the tile

    __shared__ __attribute__((aligned(16))) short Ks[2][32 * 256]; // 32 KB
    __shared__ __attribute__((aligned(16))) short Ps[2][64 * 32];  //  8 KB

    // Q frags: rows m0 + mh + ms*16 + lr
    bf16x8 qf[2][8];
    #pragma unroll
    for (int ms = 0; ms < 2; ++ms) {
        const int mrow = m0 + mh + ms * 16 + lr;
        const short* qrow = e + (size_t)mrow * 256;
        #pragma unroll
        for (int kc = 0; kc < 8; ++kc)
            qf[ms][kc] = *(const bf16x8*)(qrow + (((kc * 4 + q) ^ (mrow & 7)) << 3));
    }

    f32x4 agg[16];
    #pragma unroll
    for (int i = 0; i < 16; ++i) agg[i] = f32x4{0.f, 0.f, 0.f, 0.f};

    const int jbase = jz * tiles_per_split;
    const int wub = t & ~63;                   // wave-uniform thread base

    // prologue: stage tile 0 (16 KB) into Ks[0]
    {
        const short* src = e + (size_t)(jbase * 32) * 256;
        #pragma unroll
        for (int it = 0; it < 4; ++it)
            cp16_async(src + (size_t)(it * 256 + t) * 8,
                       &Ks[0][(size_t)(it * 256 + wub) * 8]);
    }
    __syncthreads();

    for (int jt = 0; jt < tiles_per_split; ++jt) {
        const int cur = jt & 1, nxt = cur ^ 1;
        const int j0 = (jbase + jt) * 32;

        // async prefetch of next K tile (drains at the barrier)
        if (jt + 1 < tiles_per_split) {
            const short* src = e + (size_t)(j0 + 32) * 256;
            #pragma unroll
            for (int it = 0; it < 4; ++it)
                cp16_async(src + (size_t)(it * 256 + t) * 8,
                           &Ks[nxt][(size_t)(it * 256 + wub) * 8]);
        }

        // vf register prefetch (B-frag of V, K=32 = whole tile)
        bf16x8 vfr[4];
        #pragma unroll
        for (int nt = 0; nt < 4; ++nt) {
            int n = w * 64 + nt * 16 + lr;
            vfr[nt] = *(const bf16x8*)(Xt + (size_t)n * 8192 + j0 + q * 8);
        }

        // S^T quadrant: wave reads only its 16 K-rows (jq .. jq+15)
        const short* Kb = &Ks[cur][0];
        f32x4 s[2];
        s[0] = f32x4{0.f, 0.f, 0.f, 0.f};
        s[1] = f32x4{0.f, 0.f, 0.f, 0.f};
        #pragma unroll
        for (int kc = 0; kc < 8; ++kc) {
            int row = jq + lr;
            bf16x8 kf = *(const bf16x8*)&Kb[row * 256 + (((kc*4 + q) ^ (row & 7)) << 3)];
            #pragma unroll
            for (int ms = 0; ms < 2; ++ms)
                s[ms] = __builtin_amdgcn_mfma_f32_16x16x32_bf16(
                    kf, qf[ms][kc], s[ms], 0, 0, 0);
        }

        // P scatter: 4 consecutive j at fixed m -> one aligned b64 each
        #pragma unroll
        for (int ms = 0; ms < 2; ++ms) {
            int mloc = mh + ms * 16 + lr;
            int jj = jq + q * 4;
            int off = mloc * 32 + (((jj >> 3) ^ (mloc & 3)) << 3) + (jj & 7);
            short4v pk = { f2bf(s[ms][0] * (1.0f/256.0f)),
                           f2bf(s[ms][1] * (1.0f/256.0f)),
                           f2bf(s[ms][2] * (1.0f/256.0f)),
                           f2bf(s[ms][3] * (1.0f/256.0f)) };
            *(short4v*)&Ps[cur][off] = pk;
        }
        __syncthreads();   // the ONLY barrier per tile

        // agg += P V : single K=32 step; pf streamed (1 live frag), vf regs
        #pragma unroll
        for (int mt = 0; mt < 4; ++mt) {
            int row = mt * 16 + lr;
            bf16x8 pf = *(const bf16x8*)&Ps[cur][row * 32 + ((q ^ (row & 3)) << 3)];
            #pragma unroll
            for (int nt = 0; nt < 4; ++nt)
                agg[mt * 4 + nt] = __builtin_amdgcn_mfma_f32_16x16x32_bf16(
                    pf, vfr[nt], agg[mt * 4 + nt], 0, 0, 0);
        }
    }

    const int colbase = 256 + (sim * gridDim.z + jz) * 256;
    #pragma unroll
    for (int mt = 0; mt < 4; ++mt)
        #pragma unroll
        for (int nt = 0; nt < 4; ++nt)
            #pragma unroll
            for (int r = 0; r < 4; ++r) {
                int m = m0 + mt * 16 + q * 4 + r;
                int n = w * 64 + nt * 16 + lr;
                h[(size_t)m * ldh + colbase + n] = f2bf(agg[mt * 4 + nt][r]);
            }
}

// ---------------------------------------------------------------- launch
extern "C" void kernel_launch(void* const* d_in, const int* in_sizes, int n_in,
                              void* d_out, int out_size, void* d_ws, size_t ws_size,
                              hipStream_t stream)
{
    const float* edge_x = (const float*)d_in[0];
    const float* W1 = (const float*)d_in[1];
    const float* b1 = (const float*)d_in[2];
    const float* W2 = (const float*)d_in[3];
    const float* b2 = (const float*)d_in[4];
    const float* Wo = (const float*)d_in[5];
    const float* bo = (const float*)d_in[6];

    const size_t need2 = (size_t)8192*1280*2 + 4194304u*3 + 131072u*2 + (size_t)1280*256*2;
    const int js = (ws_size >= need2) ? 2 : 1;
    const int H = 256 + 2 * js * 256;              // 1280 or 768

    char* ws = (char*)d_ws;
    short* h   = (short*)ws;
    short* Xt  = (short*)(ws + (size_t)8192 * H * 2);
    short* e1  = (short*)((char*)Xt + 4194304);
    short* e2  = (short*)((char*)e1 + 4194304);
    short* Wt1 = (short*)((char*)e2 + 4194304);
    short* Wt2 = (short*)((char*)Wt1 + 131072);
    short* Wto = (short*)((char*)Wt2 + 131072);

    prep_x<<<dim3(256, 8), dim3(32, 8), 0, stream>>>(edge_x, h, H, Xt);
    prep_w_all<<<dim3(8, 8, 3 + 2 * js), dim3(32, 8), 0, stream>>>(
        W1, W2, Wo, Wt1, Wt2, Wto, H, js);

    // e1 and e2 GEMMs in one dispatch (grid.z)
    gemm_bias_relu<<<dim3(128, 4, 2), 256, 0, stream>>>(
        h, H, Wt1, Wt2, 256, b1, b2, e1, e2, 1, 256, 1);
    // j-tiles of 32 rows: (8192/32)/js per split
    fused_simagg<<<dim3(128, 2, js), 256, 0, stream>>>(e1, e2, Xt, h, H, 256 / js);
    gemm_bias_relu<<<dim3(128, 4, 1), 256, 0, stream>>>(
        h, H, Wto, Wto, H, bo, bo, (float*)d_out, (float*)d_out, 0, 256, 0);
}